// Round 9
// baseline (963.388 us; speedup 1.0000x reference)
//
#include <hip/hip_runtime.h>
#include <hip/hip_bf16.h>
#include <stdint.h>

// GPTQ 4-bit linear: y = x @ dequant(qweight,qzeros,scales) + bias
// x: [4,2048,4096] fp32 -> M=8192 rows; qweight [512,4096] i32 (8 k-nibbles/word);
// qzeros [32,512] i32 (8 n-nibbles/word, z=nib+1); scales [32,4096] f32; out f32.

#define M_TOT 8192
#define N_TOT 4096
#define K_TOT 4096
#define NT    (K_TOT / 64)   // 64 K-tiles of BK=64

using bf16x8 = __attribute__((ext_vector_type(8))) __bf16;
using f32x4  = __attribute__((ext_vector_type(4))) float;

__device__ __forceinline__ unsigned short f2bf(float f) {
  unsigned u = __builtin_bit_cast(unsigned, f);
  u += 0x7fffu + ((u >> 16) & 1u);   // RNE
  return (unsigned short)(u >> 16);
}

// ---------------- x: fp32 -> bf16 ----------------
__global__ void cvt_x_kernel(const float* __restrict__ x,
                             unsigned short* __restrict__ xb, int n) {
  int stride = gridDim.x * blockDim.x * 8;
  for (int i = (blockIdx.x * blockDim.x + threadIdx.x) * 8; i < n; i += stride) {
    float4 a = *reinterpret_cast<const float4*>(x + i);
    float4 b = *reinterpret_cast<const float4*>(x + i + 4);
    unsigned short o[8] = {f2bf(a.x), f2bf(a.y), f2bf(a.z), f2bf(a.w),
                           f2bf(b.x), f2bf(b.y), f2bf(b.z), f2bf(b.w)};
    *reinterpret_cast<uint4*>(xb + i) = *reinterpret_cast<const uint4*>(o);
  }
}

// ---------------- dequant -> W^T [N][K] bf16 ----------------
__global__ void dequant_wt_kernel(const int* __restrict__ qweight,
                                  const int* __restrict__ qzeros,
                                  const float* __restrict__ scales,
                                  unsigned short* __restrict__ wt) {
  int t = blockIdx.x * blockDim.x + threadIdx.x;  // [0, N_TOT*512)
  int nn = t >> 9;
  int kw = t & 511;
  int g  = kw >> 4;
  unsigned w = (unsigned)qweight[kw * N_TOT + nn];
  float s = scales[g * N_TOT + nn];
  unsigned zw = (unsigned)qzeros[g * (N_TOT / 8) + (nn >> 3)];
  float z = (float)(((zw >> ((nn & 7) * 4)) & 15u) + 1u);
  unsigned short o[8];
#pragma unroll
  for (int j = 0; j < 8; ++j) {
    float v = s * ((float)((w >> (4 * j)) & 15u) - z);
    o[j] = f2bf(v);
  }
  *reinterpret_cast<uint4*>(wt + (size_t)nn * K_TOT + kw * 8) =
      *reinterpret_cast<const uint4*>(o);
}

// -- 256x256 GEMM, 4 waves x (128x128), 2 K-split phases/tile: C=A*Bt^T+b ----
// LDS reads/CU/K-tile: 128 b128 (vs 192 at 8x(128x64)) -> hides under MFMA.
// launch_bounds(256,1): 512-reg unified budget, no spill (r8 lesson).
__device__ __forceinline__ void gll16(const unsigned short* g, const unsigned short* l) {
  __builtin_amdgcn_global_load_lds(
      (const __attribute__((address_space(1))) void*)(uintptr_t)g,
      (__attribute__((address_space(3))) void*)(uintptr_t)l, 16, 0, 0);
}

__global__ __launch_bounds__(256, 1) void gemm_bigwave_kernel(
    const unsigned short* __restrict__ A,   // [M_TOT][K_TOT] bf16
    const unsigned short* __restrict__ B,   // [N_TOT][K_TOT] bf16 (W^T)
    const float* __restrict__ bias,
    float* __restrict__ C) {
  __shared__ __align__(16) unsigned short As[2 * 256 * 64];   // 64 KB
  __shared__ __align__(16) unsigned short Bs[2 * 256 * 64];   // 64 KB

  int bid = blockIdx.x;                    // 512 blocks, 512 % 8 == 0
  int swz = (bid & 7) * 64 + (bid >> 3);   // bijective XCD swizzle (T1)
  int bm = swz & 31, bn = swz >> 5;        // 32 x 16 tiles
  int m0 = bm * 256, n0 = bn * 256;

  int t = threadIdx.x;                     // 256 threads = 4 waves
  int lane = t & 63;
  int wave = t >> 6;                       // 0..3
  int wr = wave >> 1, wc = wave & 1;       // 2 (M) x 2 (N), 128x128 per wave
  int lr = lane & 15, kq = lane >> 4;

  // Staging: tile = 256 rows x 64 cols bf16 = 32 KB = 2048 16B-chunks.
  // Thread t covers chunks c = g*256 + t (g=0..7): row = g*32 + (t>>3),
  // physical slot p = t&7. Swizzle (round-3 verified, 0 conflicts): physical
  // chunk p holds logical chunk p ^ (row&7); row&7 == (t>>3)&7 for all g.
  int rowL0 = t >> 3;                                   // 0..31
  int jlog  = ((t & 7) ^ (rowL0 & 7)) * 8;              // element offset in row
  const unsigned short* aG = A + (size_t)(m0 + rowL0) * K_TOT + jlog;
  const unsigned short* bG = B + (size_t)(n0 + rowL0) * K_TOT + jlog;

  // Swizzled read bases; s half-select composed with XOR (round-2 lesson).
  unsigned rbA = (unsigned)((wr * 128 + lr) * 128 + ((kq * 16) ^ ((lr & 7) << 4)));
  unsigned rbB = (unsigned)((wc * 128 + lr) * 128 + ((kq * 16) ^ ((lr & 7) << 4)));

  f32x4 acc[8][8] = {};                    // 256 regs (AGPR-class)
  bf16x8 avA[8], bhA[8], avB[8], bhB[8];   // 128 regs, static ping-pong

  // STAGE one full tile (8 glls per thread, 16B each).
#define STAGE(matG, ldsArr, tile)                                                 \
  do {                                                                            \
    const unsigned short* _g = (matG) + (size_t)(tile) * 64;                      \
    unsigned short* _l = (ldsArr) + ((tile) & 1) * 16384 + t * 8;                 \
    _Pragma("unroll")                                                             \
    for (int _g8 = 0; _g8 < 8; ++_g8)                                             \
      gll16(_g + (size_t)_g8 * 32 * K_TOT, _l + _g8 * 2048);                      \
  } while (0)

  // Prologue: tiles 0 and 1.
  STAGE(aG, As, 0);
  STAGE(bG, Bs, 0);
  STAGE(aG, As, 1);
  STAGE(bG, Bs, 1);
  asm volatile("s_waitcnt vmcnt(16)" ::: "memory");  // tile-0 A+B landed
  __builtin_amdgcn_s_barrier();
  __builtin_amdgcn_sched_barrier(0);

  // Preload tile-0 s=0 operands.
#pragma unroll
  for (int m = 0; m < 8; ++m)
    avA[m] = *(const bf16x8*)((const char*)As + (rbA + m * 2048));
#pragma unroll
  for (int n = 0; n < 8; ++n)
    bhA[n] = *(const bf16x8*)((const char*)Bs + (rbB + n * 2048));

#pragma unroll 2
  for (int tt = 0; tt < NT; ++tt) {
    const char* aBuf  = (const char*)As + (tt & 1) * 32768;
    const char* bBuf  = (const char*)Bs + (tt & 1) * 32768;
    const char* aNext = (const char*)As + ((tt + 1) & 1) * 32768;
    const char* bNext = (const char*)Bs + ((tt + 1) & 1) * 32768;

    // ---------------- phase 0: compute s=0, read s=1 of tile t --------------
#pragma unroll
    for (int m = 0; m < 8; ++m)
      avB[m] = *(const bf16x8*)(aBuf + ((rbA + m * 2048) ^ 64));
#pragma unroll
    for (int n = 0; n < 8; ++n)
      bhB[n] = *(const bf16x8*)(bBuf + ((rbB + n * 2048) ^ 64));
    __builtin_amdgcn_sched_barrier(0);

    __builtin_amdgcn_s_setprio(1);
#pragma unroll
    for (int m = 0; m < 8; ++m)
#pragma unroll
      for (int n = 0; n < 8; ++n)
        acc[m][n] = __builtin_amdgcn_mfma_f32_16x16x32_bf16(
            avA[m], bhA[n], acc[m][n], 0, 0, 0);
    __builtin_amdgcn_s_setprio(0);

    // Retire tile-(t+1) stages (issued ph1 of t-1, ~1 phase = ~1200cyc ago).
    asm volatile("s_waitcnt vmcnt(0)" ::: "memory");
    // s=1 reads of THIS buffer complete -> ph1's same-buffer stages are safe.
    asm volatile("s_waitcnt lgkmcnt(0)" ::: "memory");
    __builtin_amdgcn_s_barrier();

    // ---------------- phase 1: compute s=1, read s=0 of tile t+1 ------------
    if (tt + 1 < NT) {
#pragma unroll
      for (int m = 0; m < 8; ++m)
        avA[m] = *(const bf16x8*)(aNext + (rbA + m * 2048));
#pragma unroll
      for (int n = 0; n < 8; ++n)
        bhA[n] = *(const bf16x8*)(bNext + (rbB + n * 2048));
    }
    __builtin_amdgcn_sched_barrier(0);

    __builtin_amdgcn_s_setprio(1);
#pragma unroll
    for (int m = 0; m < 8; ++m)
#pragma unroll
      for (int n = 0; n < 8; ++n)
        acc[m][n] = __builtin_amdgcn_mfma_f32_16x16x32_bf16(
            avB[m], bhB[n], acc[m][n], 0, 0, 0);
    __builtin_amdgcn_s_setprio(0);

    // Stage tile t+2 into As[t&1]/Bs[t&1]; all reads of those buffers
    // completed before the ph0-end lgkmcnt(0)+barrier.
    if (tt + 2 < NT) {
      STAGE(aG, As, tt + 2);
      STAGE(bG, Bs, tt + 2);
    }
    asm volatile("s_waitcnt lgkmcnt(0)" ::: "memory");
    __builtin_amdgcn_s_barrier();
  }
#undef STAGE

  // Epilogue: C/D layout col=lane&15, row=(lane>>4)*4+reg (m89-verified).
#pragma unroll
  for (int n = 0; n < 8; ++n) {
    int ncol = n0 + wc * 128 + n * 16 + lr;
    float bz = bias[ncol];
#pragma unroll
    for (int m = 0; m < 8; ++m) {
      int mrow = m0 + wr * 128 + m * 16 + kq * 4;
#pragma unroll
      for (int r = 0; r < 4; ++r)
        C[(size_t)(mrow + r) * N_TOT + ncol] = acc[m][n][r] + bz;
    }
  }
}

extern "C" void kernel_launch(void* const* d_in, const int* in_sizes, int n_in,
                              void* d_out, int out_size, void* d_ws, size_t ws_size,
                              hipStream_t stream) {
  const float* x       = (const float*)d_in[0];
  const int*   qweight = (const int*)d_in[1];
  const int*   qzeros  = (const int*)d_in[2];
  const float* scales  = (const float*)d_in[3];
  const float* bias    = (const float*)d_in[4];
  float* out = (float*)d_out;

  const size_t xb_bytes = (size_t)M_TOT * K_TOT * 2;   // 64 MB
  const size_t wt_bytes = (size_t)N_TOT * K_TOT * 2;   // 32 MB
  if (ws_size < xb_bytes + wt_bytes) return;

  unsigned short* Xb = (unsigned short*)d_ws;
  unsigned short* Wt = (unsigned short*)((char*)d_ws + xb_bytes);

  cvt_x_kernel<<<2048, 256, 0, stream>>>(x, Xb, M_TOT * K_TOT);
  dequant_wt_kernel<<<(N_TOT * 512) / 256, 256, 0, stream>>>(qweight, qzeros, scales, Wt);

  dim3 grid((M_TOT / 256) * (N_TOT / 256));  // 512
  gemm_bigwave_kernel<<<grid, 256, 0, stream>>>(Xb, Wt, bias, out);
}

// Round 10
// 281.007 us; speedup vs baseline: 3.4283x; 3.4283x over previous
//
#include <hip/hip_runtime.h>
#include <hip/hip_bf16.h>
#include <stdint.h>

// GPTQ 4-bit linear: y = x @ dequant(qweight,qzeros,scales) + bias
// x: [4,2048,4096] fp32 -> M=8192 rows; qweight [512,4096] i32 (8 k-nibbles/word);
// qzeros [32,512] i32 (8 n-nibbles/word, z=nib+1); scales [32,4096] f32; out f32.

#define M_TOT 8192
#define N_TOT 4096
#define K_TOT 4096
#define NT    (K_TOT / 64)   // 64 K-tiles of BK=64

using bf16x8 = __attribute__((ext_vector_type(8))) __bf16;
using f32x4  = __attribute__((ext_vector_type(4))) float;

__device__ __forceinline__ unsigned short f2bf(float f) {
  unsigned u = __builtin_bit_cast(unsigned, f);
  u += 0x7fffu + ((u >> 16) & 1u);   // RNE
  return (unsigned short)(u >> 16);
}

// ---------------- x: fp32 -> bf16 ----------------
__global__ void cvt_x_kernel(const float* __restrict__ x,
                             unsigned short* __restrict__ xb, int n) {
  int stride = gridDim.x * blockDim.x * 8;
  for (int i = (blockIdx.x * blockDim.x + threadIdx.x) * 8; i < n; i += stride) {
    float4 a = *reinterpret_cast<const float4*>(x + i);
    float4 b = *reinterpret_cast<const float4*>(x + i + 4);
    unsigned short o[8] = {f2bf(a.x), f2bf(a.y), f2bf(a.z), f2bf(a.w),
                           f2bf(b.x), f2bf(b.y), f2bf(b.z), f2bf(b.w)};
    *reinterpret_cast<uint4*>(xb + i) = *reinterpret_cast<const uint4*>(o);
  }
}

// ---------------- dequant -> W^T [N][K] bf16 ----------------
__global__ void dequant_wt_kernel(const int* __restrict__ qweight,
                                  const int* __restrict__ qzeros,
                                  const float* __restrict__ scales,
                                  unsigned short* __restrict__ wt) {
  int t = blockIdx.x * blockDim.x + threadIdx.x;  // [0, N_TOT*512)
  int nn = t >> 9;
  int kw = t & 511;
  int g  = kw >> 4;
  unsigned w = (unsigned)qweight[kw * N_TOT + nn];
  float s = scales[g * N_TOT + nn];
  unsigned zw = (unsigned)qzeros[g * (N_TOT / 8) + (nn >> 3)];
  float z = (float)(((zw >> ((nn & 7) * 4)) & 15u) + 1u);
  unsigned short o[8];
#pragma unroll
  for (int j = 0; j < 8; ++j) {
    float v = s * ((float)((w >> (4 * j)) & 15u) - z);
    o[j] = f2bf(v);
  }
  *reinterpret_cast<uint4*>(wt + (size_t)nn * K_TOT + kw * 8) =
      *reinterpret_cast<const uint4*>(o);
}

// -- 256x256 GEMM, r5 structure with 2 barriers/tile (wave-skew overlap) -----
__device__ __forceinline__ void gll16(const unsigned short* g, const unsigned short* l) {
  __builtin_amdgcn_global_load_lds(
      (const __attribute__((address_space(1))) void*)(uintptr_t)g,
      (__attribute__((address_space(3))) void*)(uintptr_t)l, 16, 0, 0);
}

__global__ __launch_bounds__(512, 2) void gemm_8phase_kernel(
    const unsigned short* __restrict__ A,   // [M_TOT][K_TOT] bf16
    const unsigned short* __restrict__ B,   // [N_TOT][K_TOT] bf16 (W^T)
    const float* __restrict__ bias,
    float* __restrict__ C) {
  __shared__ __align__(16) unsigned short As[2 * 256 * 64];   // 64 KB
  __shared__ __align__(16) unsigned short Bs[2 * 256 * 64];   // 64 KB

  int bid = blockIdx.x;                    // 512 blocks, 512 % 8 == 0
  int swz = (bid & 7) * 64 + (bid >> 3);   // bijective XCD swizzle (T1)
  int bm = swz & 31, bn = swz >> 5;        // 32 x 16 tiles
  int m0 = bm * 256, n0 = bn * 256;

  int t = threadIdx.x;
  int lane = t & 63;
  int wave = t >> 6;                       // 8 waves
  int wr = wave >> 2, wc = wave & 3;       // 2 (M) x 4 (N)
  int lr = lane & 15, kq = lane >> 4;

  // Staging (round-3 verified, 0 conflicts): physical chunk p = t&7 of rows
  // rowL0, rowL0+64; source pre-permuted j_log = (t&7) ^ (rowL0&7).
  int rowL0 = t >> 3;
  int jlog  = ((t & 7) ^ (rowL0 & 7)) * 8;
  const unsigned short* aG = A + (size_t)(m0 + rowL0) * K_TOT + jlog;
  const unsigned short* bG = B + (size_t)(n0 + rowL0) * K_TOT + jlog;

  // Swizzled read bases; s half-select composed with XOR (round-2 lesson).
  unsigned rbA = (unsigned)((wr * 128 + lr) * 128 + ((kq * 16) ^ ((lr & 7) << 4)));
  unsigned rbB = (unsigned)((wc * 64  + lr) * 128 + ((kq * 16) ^ ((lr & 7) << 4)));

  f32x4 acc[8][4] = {};
  bf16x8 av[2][2][2];   // [pingpong][mm][s] — next-phase A frags
  bf16x8 bh[2][4][2];   // [tile parity][n][s] — B frags, double-buffered

#define STAGE(matG, ldsArr, tile, h)                                              \
  do {                                                                            \
    const unsigned short* _g = (matG) + (size_t)(h) * 128 * K_TOT +               \
                               (size_t)(tile) * 64;                               \
    const unsigned short* _l = (ldsArr) + ((tile) & 1) * 16384 + (h) * 8192 +     \
                               t * 8;                                             \
    gll16(_g, _l);                                                                \
    gll16(_g + (size_t)64 * K_TOT, _l + 4096);                                    \
  } while (0)

  // Prologue: A(0), B(0) (8 oldest glls), then B(1). A(1) stages in tile 0.
  STAGE(aG, As, 0, 0);
  STAGE(aG, As, 0, 1);
  STAGE(bG, Bs, 0, 0);
  STAGE(bG, Bs, 0, 1);
  STAGE(bG, Bs, 1, 0);
  STAGE(bG, Bs, 1, 1);
  asm volatile("s_waitcnt vmcnt(4)" ::: "memory");  // A(0),B(0) landed
  __builtin_amdgcn_s_barrier();
  __builtin_amdgcn_sched_barrier(0);

  // Preload tile-0 operands: bh[0] = B(0), av[0] = A(0) phase-0 frags.
  {
    const char* aB0 = (const char*)As;
    const char* bB0 = (const char*)Bs;
#pragma unroll
    for (int n = 0; n < 4; ++n)
#pragma unroll
      for (int s = 0; s < 2; ++s)
        bh[0][n][s] = *(const bf16x8*)(bB0 + ((rbB + n * 2048) ^ (s * 64)));
#pragma unroll
    for (int mm = 0; mm < 2; ++mm)
#pragma unroll
      for (int s = 0; s < 2; ++s)
        av[0][mm][s] = *(const bf16x8*)(aB0 + ((rbA + mm * 2048) ^ (s * 64)));
  }

#pragma unroll 2
  for (int tt = 0; tt < NT; ++tt) {
    const char* aBuf = (const char*)As + (tt & 1) * 32768;

#pragma unroll
    for (int q = 0; q < 4; ++q) {
      // --- MFMA on operands prefetched last phase (own lgkm already paid) ---
      __builtin_amdgcn_s_setprio(1);
#pragma unroll
      for (int s = 0; s < 2; ++s)
#pragma unroll
        for (int mm = 0; mm < 2; ++mm)
#pragma unroll
          for (int n = 0; n < 4; ++n)
            acc[2 * q + mm][n] = __builtin_amdgcn_mfma_f32_16x16x32_bf16(
                av[q & 1][mm][s], bh[tt & 1][n][s], acc[2 * q + mm][n], 0, 0, 0);
      __builtin_amdgcn_s_setprio(0);

      // --- prefetch next phase's A frags (reads parity t&1; A stages write
      // the other parity -> hazard-free without a barrier) ---
      if (q < 3) {
#pragma unroll
        for (int mm = 0; mm < 2; ++mm)
#pragma unroll
          for (int s = 0; s < 2; ++s)
            av[(q + 1) & 1][mm][s] = *(const bf16x8*)(
                aBuf + ((rbA + (2 * (q + 1) + mm) * 2048) ^ (s * 64)));
      }

      // --- stages: q0: A(t+1)h0; q1: A(t+1)h1; q2: B(t+2)h0; q3: B(t+2)h1.
      // Hazards: A stages vs A(t-1) readers -> delivered before q3-barrier of
      // t-1 (operand waits) ✓. B(t+2) stages vs B(t) readers (bh cross-read,
      // delivered before each wave's q0 MFMA) -> q1-end barrier orders ✓.
      if (q == 0 && tt + 1 < NT) STAGE(aG, As, tt + 1, 0);
      if (q == 1 && tt + 1 < NT) STAGE(aG, As, tt + 1, 1);
      if (q == 2 && tt + 2 < NT) STAGE(bG, Bs, tt + 2, 0);
      if (q == 3) {
        if (tt + 2 < NT) STAGE(bG, Bs, tt + 2, 1);
        // Ledger at this point (oldest first): B(t+1):4 (prev tile q2/q3),
        // A(t+1):4 (q0/q1), B(t+2):4 (q2/q3) = 12 outstanding.
        // vmcnt(4) retires B(t+1)+A(t+1) — exactly what the cross-reads
        // below consume. Never 0 mid-loop (T4).
        if (tt >= NT - 2) asm volatile("s_waitcnt vmcnt(0)" ::: "memory");
        else              asm volatile("s_waitcnt vmcnt(4)" ::: "memory");
      }

      // Only 2 barriers per tile: q1-end (B-stage WAR) and q3-end (publish
      // stages for cross-reads). Waves may skew ~2 phases between barriers,
      // overlapping one wave's ds_reads with another's MFMA cluster.
      if (q == 1 || q == 3) __builtin_amdgcn_s_barrier();

      if (q == 3) {
        __builtin_amdgcn_sched_barrier(0);   // pin cross-reads below barrier
        if (tt + 1 < NT) {                   // cross-tile operand preload
          const char* aN = (const char*)As + ((tt + 1) & 1) * 32768;
          const char* bN = (const char*)Bs + ((tt + 1) & 1) * 32768;
#pragma unroll
          for (int n = 0; n < 4; ++n)
#pragma unroll
            for (int s = 0; s < 2; ++s)
              bh[(tt + 1) & 1][n][s] =
                  *(const bf16x8*)(bN + ((rbB + n * 2048) ^ (s * 64)));
#pragma unroll
          for (int mm = 0; mm < 2; ++mm)
#pragma unroll
            for (int s = 0; s < 2; ++s)
              av[0][mm][s] = *(const bf16x8*)(aN + ((rbA + mm * 2048) ^ (s * 64)));
        }
      }
    }
  }
#undef STAGE

  // Epilogue: C/D layout col=lane&15, row=(lane>>4)*4+reg (m89-verified).
#pragma unroll
  for (int n = 0; n < 4; ++n) {
    int ncol = n0 + wc * 64 + n * 16 + lr;
    float bz = bias[ncol];
#pragma unroll
    for (int m = 0; m < 8; ++m) {
      int mrow = m0 + wr * 128 + m * 16 + kq * 4;
#pragma unroll
      for (int r = 0; r < 4; ++r)
        C[(size_t)(mrow + r) * N_TOT + ncol] = acc[m][n][r] + bz;
    }
  }
}

extern "C" void kernel_launch(void* const* d_in, const int* in_sizes, int n_in,
                              void* d_out, int out_size, void* d_ws, size_t ws_size,
                              hipStream_t stream) {
  const float* x       = (const float*)d_in[0];
  const int*   qweight = (const int*)d_in[1];
  const int*   qzeros  = (const int*)d_in[2];
  const float* scales  = (const float*)d_in[3];
  const float* bias    = (const float*)d_in[4];
  float* out = (float*)d_out;

  const size_t xb_bytes = (size_t)M_TOT * K_TOT * 2;   // 64 MB
  const size_t wt_bytes = (size_t)N_TOT * K_TOT * 2;   // 32 MB
  if (ws_size < xb_bytes + wt_bytes) return;

  unsigned short* Xb = (unsigned short*)d_ws;
  unsigned short* Wt = (unsigned short*)((char*)d_ws + xb_bytes);

  cvt_x_kernel<<<2048, 256, 0, stream>>>(x, Xb, M_TOT * K_TOT);
  dequant_wt_kernel<<<(N_TOT * 512) / 256, 256, 0, stream>>>(qweight, qzeros, scales, Wt);

  dim3 grid((M_TOT / 256) * (N_TOT / 256));  // 512
  gemm_8phase_kernel<<<grid, 512, 0, stream>>>(Xb, Wt, bias, out);
}